// Round 7
// baseline (274.177 us; speedup 1.0000x reference)
//
#include <hip/hip_runtime.h>

#define K_DIM 8192
#define M_REAL 2000
#define N_REAL 2000
#define M_PAD 2048
#define N_PAD 2048

#define BM 128
#define BN 128
#define BK 32
#define NSTEP (K_DIM / BK)       // 256 K-steps per block (no split-K)

// fused prep block ranges (init phase deleted: gemm overwrites out)
#define NB_W 1024
#define NB_X 2048

typedef __bf16 bf16x8 __attribute__((ext_vector_type(8)));
typedef float f32x4 __attribute__((ext_vector_type(4)));
typedef float fvec4 __attribute__((ext_vector_type(4)));

__device__ __forceinline__ unsigned short f2bf(float f) {
    union { float f; unsigned u; } v; v.f = f;
    unsigned r = v.u + 0x7FFFu + ((v.u >> 16) & 1u);  // RNE; inputs are finite normals
    return (unsigned short)(r >> 16);
}

__device__ __forceinline__ unsigned pk2(float a, float b) {
    return (unsigned)f2bf(a) | ((unsigned)f2bf(b) << 16);
}

__device__ __forceinline__ void async16(const void* g, void* l) {
    __builtin_amdgcn_global_load_lds((__attribute__((address_space(1))) void*)(g),
                                     (__attribute__((address_space(3))) void*)(l),
                                     16, 0, 0);
}

// ---------------------------------------------------------------------------
// Fused prep (one dispatch) — conversion phases unchanged (near-roofline);
// out-init phase DELETED (gemm now writes out = acc + bias directly):
//   blocks [0,1024):       W f32 -> Wb bf16 [2048][8192], grid-stride, 32B ld/16B st
//   blocks [1024,3072):    X [8192][2000] f32 -> XT bf16 [2048][8192] transpose,
//                          conflict-free LDS (row stride 65 words === 1 mod 32)
__global__ __launch_bounds__(256) void prep_kernel(const float* __restrict__ W,
                                                   const float* __restrict__ X,
                                                   unsigned short* __restrict__ Wb,
                                                   unsigned short* __restrict__ XT) {
    __shared__ unsigned short T[64][130];
    int bid = blockIdx.x;
    if (bid < NB_W) {
        unsigned tid = bid * 256u + threadIdx.x;
#pragma unroll
        for (unsigned i = 0; i < 8; ++i) {
            unsigned e = (i * (1024u * 256u) + tid) * 8u;       // element index
            uint4 o = make_uint4(0u, 0u, 0u, 0u);
            if (e < (unsigned)(M_REAL * K_DIM)) {
                fvec4 f0 = __builtin_nontemporal_load((const fvec4*)(W + e));
                fvec4 f1 = __builtin_nontemporal_load((const fvec4*)(W + e + 4));
                o.x = pk2(f0.x, f0.y);
                o.y = pk2(f0.z, f0.w);
                o.z = pk2(f1.x, f1.y);
                o.w = pk2(f1.z, f1.w);
            }
            *(uint4*)(Wb + e) = o;
        }
    } else {
        int b = bid - NB_W;
        int k0 = (b & 63) << 7;        // 0..8064 step 128
        int n0 = (b >> 6) << 6;        // 0..1984 step 64
        int t = threadIdx.x;
        int c = t & 15;
        int r = t >> 4;
        int nl = c << 2;               // local n base (x4)
        int n = n0 + nl;
        bool valid = (n < N_REAL);
#pragma unroll
        for (int p = 0; p < 4; ++p) {
            int kl = (r << 1) + (p << 5);
            fvec4 v0 = {0.f, 0.f, 0.f, 0.f};
            fvec4 v1 = {0.f, 0.f, 0.f, 0.f};
            if (valid) {
                v0 = __builtin_nontemporal_load((const fvec4*)(X + (k0 + kl) * N_REAL + n));
                v1 = __builtin_nontemporal_load((const fvec4*)(X + (k0 + kl + 1) * N_REAL + n));
            }
            *(unsigned*)&T[nl + 0][kl] = pk2(v0.x, v1.x);
            *(unsigned*)&T[nl + 1][kl] = pk2(v0.y, v1.y);
            *(unsigned*)&T[nl + 2][kl] = pk2(v0.z, v1.z);
            *(unsigned*)&T[nl + 3][kl] = pk2(v0.w, v1.w);
        }
        __syncthreads();
#pragma unroll
        for (int it = 0; it < 4; ++it) {
            int nl2 = r + (it << 4);
            int kl2 = c << 3;
            const unsigned* tp = (const unsigned*)&T[nl2][kl2];
            uint4 o;
            o.x = tp[0]; o.y = tp[1]; o.z = tp[2]; o.w = tp[3];
            *(uint4*)(XT + (((n0 + nl2) << 13) + k0 + kl2)) = o;
        }
    }
}

// ---------------------------------------------------------------------------
// R7: NO-SPLIT-K GEMM. Theory: the 112-117 us invariant across four K-loop
// structures (R2/R4/R5/R6) was the shared epilogue -- 16.7M fp32 atomicAdd
// RMW (~54 us at ~1 atomic/cyc/L2-channel), flooding at end-of-kernel with
// nothing left to overlap. SPLITK=1 replaces it with plain coalesced stores
// of acc + bias[n] (16 MB, ~3 us) and deletes prep_init.
//
// 128x128 tile, BK=32, 512 thr (8 waves = 2m x 4n, wave-tile 64x32,
// acc[4][2]), NSTEP=256, grid 256 (1 block/CU; R5~=R6 showed waves/SIMD
// doesn't move the needle). K-loop = R6 structure verbatim: 2-deep LDS
// (32 KiB), global_load_lds with pre-swizzled source, 0-conflict T2 swizzle
// [R4-verified], plain __syncthreads (vmcnt drain) per step.
__global__ __launch_bounds__(512, 2) void gemm_kernel(const unsigned short* __restrict__ Wb,
                                                      const unsigned short* __restrict__ XT,
                                                      const float* __restrict__ bias,
                                                      float* __restrict__ out) {
    __shared__ __align__(16) char smA[2 * 8192];   // 2 x (128 rows x 64 B)
    __shared__ __align__(16) char smB[2 * 8192];

    int f = blockIdx.x;
    int xcd = f & 7;
    int local = f >> 3;                    // 0..31
    int bx = (xcd & 3) * 4 + (local & 3);  // 0..15
    int by = (xcd >> 2) * 8 + (local >> 2);// 0..15

    int t = threadIdx.x;
    int w = t >> 6;                // 0..7
    int l = t & 63;
    int lane16 = l & 15;
    int quad = l >> 4;
    int wr = w >> 2;               // 0..1  (m-half, 64 rows)
    int wc = w & 3;                // 0..3  (n-quarter, 32 cols)
    int m0 = by * BM;
    int n0 = bx * BN;

    f32x4 acc[4][2] = {};

    // ---- staging map: 512 thr cover one 8 KB operand tile each for A and B.
    //      thread t -> row t>>2 (0..127), phys chunk t&3; LDS dest linear
    //      (wave w writes bytes w*1024..+1023 of each tile).
    //      Pre-swizzled source chunk: (t&3) ^ ((row>>1)&3) = (t&3)^((t>>3)&3).
    int rowS = t >> 2;
    int lc   = (t & 3) ^ ((t >> 3) & 3);
    const unsigned short* gA = Wb + (long long)(m0 + rowS) * K_DIM + lc * 8;
    const unsigned short* gB = XT + (long long)(n0 + rowS) * K_DIM + lc * 8;

#define STAGE(BUF, KOFF) do { \
        int bo_ = (BUF) * 8192 + w * 1024; \
        async16(gA + (KOFF), smA + bo_); \
        async16(gB + (KOFF), smB + bo_); \
    } while (0)

    // ---- reader-side swizzled row offsets (bytes within one 8 KB buffer) ----
    // frag row = base + i*16 + lane16 -> (row>>1)&3 == (lane16>>1)&3.
    int swz = ((quad ^ ((lane16 >> 1) & 3)) << 4);
    int arow = (wr * 64 + lane16) * 64 + swz;
    int brow = (wc * 32 + lane16) * 64 + swz;

    // ---- prologue ----
    STAGE(0, 0);
    __syncthreads();

    for (int s = 0; s < NSTEP; ++s) {
        if (s + 1 < NSTEP)
            STAGE((s + 1) & 1, (s + 1) * BK);

        int bo = (s & 1) * 8192;
        const char* Ab = smA + bo + arow;
        const char* Bb = smB + bo + brow;
        bf16x8 a0 = *(const bf16x8*)(Ab);
        bf16x8 a1 = *(const bf16x8*)(Ab + 1024);
        bf16x8 a2 = *(const bf16x8*)(Ab + 2048);
        bf16x8 a3 = *(const bf16x8*)(Ab + 3072);
        bf16x8 b0 = *(const bf16x8*)(Bb);
        bf16x8 b1 = *(const bf16x8*)(Bb + 1024);

        acc[0][0] = __builtin_amdgcn_mfma_f32_16x16x32_bf16(a0, b0, acc[0][0], 0, 0, 0);
        acc[0][1] = __builtin_amdgcn_mfma_f32_16x16x32_bf16(a0, b1, acc[0][1], 0, 0, 0);
        acc[1][0] = __builtin_amdgcn_mfma_f32_16x16x32_bf16(a1, b0, acc[1][0], 0, 0, 0);
        acc[1][1] = __builtin_amdgcn_mfma_f32_16x16x32_bf16(a1, b1, acc[1][1], 0, 0, 0);
        acc[2][0] = __builtin_amdgcn_mfma_f32_16x16x32_bf16(a2, b0, acc[2][0], 0, 0, 0);
        acc[2][1] = __builtin_amdgcn_mfma_f32_16x16x32_bf16(a2, b1, acc[2][1], 0, 0, 0);
        acc[3][0] = __builtin_amdgcn_mfma_f32_16x16x32_bf16(a3, b0, acc[3][0], 0, 0, 0);
        acc[3][1] = __builtin_amdgcn_mfma_f32_16x16x32_bf16(a3, b1, acc[3][1], 0, 0, 0);

        if (s + 1 < NSTEP)
            __syncthreads();       // drains vmcnt/lgkm + barrier (m97 semantics)
    }
#undef STAGE

    // Epilogue: plain stores, out = acc + bias[n]. No atomics, no init pass.
    // C/D layout col = lane&15, row = quad*4 + reg  [m89-verified]
#pragma unroll
    for (int j = 0; j < 2; ++j) {
        int n = n0 + wc * 32 + j * 16 + lane16;
        if (n >= N_REAL) continue;
        float bv = bias[n];
#pragma unroll
        for (int i = 0; i < 4; ++i) {
            int mbase = m0 + wr * 64 + i * 16 + quad * 4;
#pragma unroll
            for (int r = 0; r < 4; ++r) {
                int m = mbase + r;
                if (m < M_REAL)
                    out[(long long)m * N_REAL + n] = acc[i][j][r] + bv;
            }
        }
    }
}

// ---------------------------------------------------------------------------
extern "C" void kernel_launch(void* const* d_in, const int* in_sizes, int n_in,
                              void* d_out, int out_size, void* d_ws, size_t ws_size,
                              hipStream_t stream) {
    const float* W    = (const float*)d_in[0];  // [2000][8192]
    const float* bias = (const float*)d_in[1];  // [2000]
    const float* X    = (const float*)d_in[2];  // [8192][2000]
    float* out = (float*)d_out;

    unsigned short* Wb = (unsigned short*)d_ws;                 // [2048][8192] bf16
    unsigned short* XT = Wb + (long long)M_PAD * K_DIM;         // [2048][8192] bf16

    prep_kernel<<<NB_W + NB_X, 256, 0, stream>>>(W, X, Wb, XT);

    gemm_kernel<<<(N_PAD / BN) * (M_PAD / BM), 512, 0, stream>>>(Wb, XT, bias, out);
}